// Round 10
// baseline (140.676 us; speedup 1.0000x reference)
//
#include <hip/hip_runtime.h>
#include <math.h>

// Capsule routing B=32, N=1024(j), D=256(k), NC=32(i), DC=64(d). Factored
// (no u_hat), MFMA 16x16x32 bf16.
// Round-10:
//  - Ubf16 pre-converted + pre-rotated (k -> (k+8*(j&15))&255) in k_init;
//    k_pass stages it with pure global_load_lds DMA (no VALU, no pad needed).
//  - w stored pre-rotated bf16 hi/lo -> DMA too.
//  - bmat logits eliminated: logits_n = U.(w1+..+wn)  (linearity), k_sv keeps
//    fp32 wsum; k_pass is identical for both passes.
// 6 plain launches, no atomics, no grid.sync.

typedef short v8s __attribute__((ext_vector_type(8)));
typedef short v4s __attribute__((ext_vector_type(4)));
typedef float v4f __attribute__((ext_vector_type(4)));

__device__ __forceinline__ unsigned short f2bf(float x) {
    unsigned u = __float_as_uint(x);
    u = u + 0x7fffu + ((u >> 16) & 1u);
    return (unsigned short)(u >> 16);
}
__device__ __forceinline__ float bf2f(unsigned short h) {
    return __uint_as_float(((unsigned)h) << 16);
}
__device__ __forceinline__ void dma16(const void* g, void* l) {
    __builtin_amdgcn_global_load_lds(
        (const __attribute__((address_space(1))) unsigned int*)g,
        (__attribute__((address_space(3))) unsigned int*)l, 16, 0, 0);
}

// ---------------------------------------------------------------------------
// k_init, grid 1152:
//  bid <  512: convert U -> Ubf16, rotated layout [b][j][(k+8*(j&15))&255]
//  bid < 1024: colsum partials t0p[b][q][k] (fp32 U, iter-0 uniform softmax)
//  else      : transpose W -> WT (2048x256)
__global__ __launch_bounds__(256) void k_init(const float* __restrict__ U,
                                              const float* __restrict__ W,
                                              float* __restrict__ t0p,
                                              float* __restrict__ WT,
                                              short* __restrict__ Ubf16) {
    int bid = blockIdx.x, tid = threadIdx.x;
    if (bid < 512) {
        int b = bid >> 4, q = bid & 15;
        const float4* U4 = (const float4*)U;
        #pragma unroll
        for (int it = 0; it < 8; ++it) {
            int idx = (it << 8) + tid;           // 0..2047
            int jl = idx >> 5, ch = idx & 31;    // row 0..63, 8-elem chunk 0..31
            int j = (q << 6) + jl;
            float4 g0 = U4[(((b << 10) + j) << 6) + (ch << 1)];
            float4 g1 = U4[(((b << 10) + j) << 6) + (ch << 1) + 1];
            int rot = ((ch << 3) + ((j & 15) << 3)) & 255;
            *(v8s*)&Ubf16[((size_t)((b << 10) + j) << 8) + rot] =
                (v8s){(short)f2bf(g0.x), (short)f2bf(g0.y),
                      (short)f2bf(g0.z), (short)f2bf(g0.w),
                      (short)f2bf(g1.x), (short)f2bf(g1.y),
                      (short)f2bf(g1.z), (short)f2bf(g1.w)};
        }
    } else if (bid < 1024) {
        int b2 = bid - 512;
        int b = b2 >> 4, q = b2 & 15;
        const float* Up = U + (((b << 10) + (q << 6)) << 8) + tid;
        float acc = 0.f;
        #pragma unroll 16
        for (int jl = 0; jl < 64; ++jl) acc += Up[jl << 8];
        t0p[(b << 12) + (q << 8) + tid] = acc * (1.0f / 1024.0f);
    } else {
        __shared__ float tile[64 * 65];
        int tix = bid - 1024;                    // 0..127
        int k0 = (tix >> 5) << 6, c0 = (tix & 31) << 6;
        int cc = tid & 63, g4 = tid >> 6;
        #pragma unroll
        for (int r = 0; r < 16; ++r) {
            int kk = (g4 << 4) + r;
            tile[kk * 65 + cc] = W[(k0 + kk) * 2048 + c0 + cc];
        }
        __syncthreads();
        int kk = tid & 63;
        #pragma unroll
        for (int r = 0; r < 16; ++r) {
            int c = (g4 << 4) + r;
            WT[(c0 + c) * 256 + k0 + kk] = tile[kk * 65 + c];
        }
    }
}

// ---------------------------------------------------------------------------
// k_sv: per (b,iG): t[k] = sum of 16 partials; s = tW_i; v = squash(.,sef);
// w = W_i v; wsum (+)= w (fp32); wbt hi/lo written bf16, PRE-ROTATED by il.
// grid 1024, block 256.
__global__ __launch_bounds__(256) void k_sv(const float* __restrict__ t0p,
                                            const float* __restrict__ tpart,
                                            const float* __restrict__ sefpart,
                                            const float* __restrict__ W,
                                            const float* __restrict__ WT,
                                            float* __restrict__ wsum,
                                            short* __restrict__ wbt_h,
                                            short* __restrict__ wbt_l,
                                            float* __restrict__ out,
                                            int mode, int writeOut) {
    __shared__ float t_lds[256];
    __shared__ float spart[256];
    __shared__ __align__(16) float v_lds[64];
    __shared__ __align__(16) v4f spartw[256];
    __shared__ float sefv_s;
    int bid = blockIdx.x, tid = threadIdx.x;
    int b = bid >> 5, iG = bid & 31;
    int bg = (b << 1) | (iG >> 4), il = iG & 15;

    float acc = 0.f;
    if (mode == 0) {
        const float* tb = t0p + (b << 12) + tid;
        #pragma unroll
        for (int q = 0; q < 16; ++q) acc += tb[q << 8];
        if (tid == 0) sefv_s = 1.0f;
    } else {
        const float* tb = tpart + (((bg << 4) + il) << 8) + tid;
        #pragma unroll
        for (int p = 0; p < 16; ++p) acc += tb[p << 18];  // stride 64*16*256
        if (tid == 0) {
            float s = 0.f;
            #pragma unroll
            for (int p = 0; p < 16; ++p) s += sefpart[(p << 10) + (bg << 4) + il];
            sefv_s = s;
        }
    }
    t_lds[tid] = acc;
    __syncthreads();

    // s-phase: (d = tid&63, kq = tid>>6), coalesced 256B W reads
    int d = tid & 63, kq = tid >> 6;
    const float* Wc = W + ((kq << 6) * 2048) + (iG << 6) + d;
    float s = 0.f;
    #pragma unroll 4
    for (int kk = 0; kk < 64; ++kk)
        s += t_lds[(kq << 6) + kk] * Wc[kk * 2048];
    spart[tid] = s;
    __syncthreads();

    if (tid < 64) {
        float sv = spart[tid] + spart[tid + 64] + spart[tid + 128] + spart[tid + 192];
        float n2 = sv * sv;
        #pragma unroll
        for (int m = 1; m < 64; m <<= 1) n2 += __shfl_xor(n2, m, 64);
        float sf = sefv_s;
        float v = sv * rsqrtf(n2 + 1e-7f * sf * sf);
        v_lds[tid] = v;
        if (writeOut) out[(bid << 6) + tid] = v;
    }
    __syncthreads();
    if (writeOut) return;

    // w-phase: (k4 = tid&63, dq = tid>>6), WT gives coalesced reads
    int k4 = tid & 63, dq = tid >> 6;
    const float4* WT4 = (const float4*)WT;
    v4f wp = {0.f, 0.f, 0.f, 0.f};
    #pragma unroll
    for (int dd = 0; dd < 16; ++dd) {
        float vv = v_lds[(dq << 4) + dd];
        float4 wt = WT4[((iG << 6) + (dq << 4) + dd) * 64 + k4];
        wp.x += vv * wt.x; wp.y += vv * wt.y; wp.z += vv * wt.z; wp.w += vv * wt.w;
    }
    spartw[(dq << 6) + k4] = wp;
    __syncthreads();
    if (tid < 64) {
        v4f w = spartw[tid] + spartw[64 + tid] + spartw[128 + tid] + spartw[192 + tid];
        float wv4[4] = {w.x, w.y, w.z, w.w};
        int wsidx = (((bg << 4) + il) << 8) + (tid << 2);
        if (mode != 0) {
            float4 old = *(const float4*)&wsum[wsidx];
            wv4[0] += old.x; wv4[1] += old.y; wv4[2] += old.z; wv4[3] += old.w;
        }
        *(float4*)&wsum[wsidx] =
            make_float4(wv4[0], wv4[1], wv4[2], wv4[3]);
        unsigned short wh[4], wl[4];
        #pragma unroll
        for (int e = 0; e < 4; ++e) {
            wh[e] = f2bf(wv4[e]);
            wl[e] = f2bf(wv4[e] - bf2f(wh[e]));
        }
        int rotk = ((tid << 2) + (il << 3)) & 255;
        int base = (((bg << 4) + il) << 8) + rotk;
        *(v4s*)&wbt_h[base] = (v4s){(short)wh[0], (short)wh[1], (short)wh[2], (short)wh[3]};
        *(v4s*)&wbt_l[base] = (v4s){(short)wl[0], (short)wl[1], (short)wl[2], (short)wl[3]};
    }
}

// ---------------------------------------------------------------------------
// k_pass v4: block = (b, p = 64-j slice, g2), grid 1024x1024. Stage U tile
// (32 KB) + w hi/lo (16 KB) via pure global_load_lds DMA (rotated layouts).
// Phase D: 16 waves = 4 j-tiles x 4 K-quarters + LDS reduce; exp on frags;
// phase T: 16 waves = 16-k N-tiles, B-frags read directly from U tile.
__global__ __launch_bounds__(1024, 8) void k_pass(const short* __restrict__ Ubf16,
                                                  const short* __restrict__ wbt_h,
                                                  const short* __restrict__ wbt_l,
                                                  float* __restrict__ tpart_out,
                                                  float* __restrict__ sefpart_out) {
    __shared__ short s_U[64 * 256];      // 32 KB, rotated [j][(k+8*(j&15))&255]
    __shared__ short s_wh[16 * 256];     // 8 KB, rotated [i][(k+8i)&255]
    __shared__ short s_wl[16 * 256];     // 8 KB
    __shared__ short s_eh[16 * 72];      // 2.25 KB [i][j] pad 8
    __shared__ short s_el[16 * 72];
    __shared__ float s_red[16 * 320];    // 20 KB [kq*4+mt][rr*20+nn]
    __shared__ float s_sefp[16 * 16];    // 1 KB          total 73.5 KB

    const int tid = threadIdx.x, wv = tid >> 6, lane = tid & 63;
    const int quad = lane >> 4, nn = lane & 15;
    const int blk = blockIdx.x;
    const int b = blk & 31, pg = blk >> 5;   // same-b blocks share XCD
    const int p = pg >> 1, g2 = pg & 1;
    const int bg = (b << 1) | g2;
    const int rowbase = (b << 10) + (p << 6);

    // ---- DMA staging (no VALU) ----
    {
        const char* ug = (const char*)Ubf16 + ((size_t)rowbase << 9);  // *512 B/row
        dma16(ug + (wv << 11) + (lane << 4), (char*)s_U + (wv << 11));
        dma16(ug + (wv << 11) + 1024 + (lane << 4), (char*)s_U + (wv << 11) + 1024);
        if (wv < 8) {
            const char* wg = (const char*)wbt_h + (bg << 13) + (wv << 10);
            dma16(wg + (lane << 4), (char*)s_wh + (wv << 10));
        } else {
            const char* wg = (const char*)wbt_l + (bg << 13) + ((wv - 8) << 10);
            dma16(wg + (lane << 4), (char*)s_wl + ((wv - 8) << 10));
        }
    }
    __syncthreads();

    // ---- phase D: wave = (mt = j-tile, kq = K-quarter) ----
    {
        const int mt = wv & 3, kq = wv >> 2;
        v4f dacc = {0.f, 0.f, 0.f, 0.f};
        #pragma unroll
        for (int c = 0; c < 2; ++c) {
            int kb = (kq << 6) + (c << 5) + (quad << 3);
            int rk = (kb + (nn << 3)) & 255;           // rotation by row&15 = nn
            v8s a  = *(const v8s*)&s_U[(((mt << 4) + nn) << 8) + rk];
            v8s bh = *(const v8s*)&s_wh[(nn << 8) + rk];
            v8s bl = *(const v8s*)&s_wl[(nn << 8) + rk];
            dacc = __builtin_amdgcn_mfma_f32_16x16x32_bf16(a, bh, dacc, 0, 0, 0);
            dacc = __builtin_amdgcn_mfma_f32_16x16x32_bf16(a, bl, dacc, 0, 0, 0);
        }
        #pragma unroll
        for (int r = 0; r < 4; ++r)
            s_red[wv * 320 + ((quad << 2) + r) * 20 + nn] = dacc[r];
    }
    __syncthreads();

    // ---- K-reduce + exp + e hi/lo + sef partials ----
    {
        const int mt2 = wv & 3, jq = wv >> 2;
        const int rr = (jq << 2) + quad;
        const int jloc = (mt2 << 4) + rr;
        float val = 0.f;
        #pragma unroll
        for (int kq = 0; kq < 4; ++kq)
            val += s_red[((kq << 2) + mt2) * 320 + rr * 20 + nn];
        float e = __expf(val);
        unsigned short eh = f2bf(e);
        s_eh[nn * 72 + jloc] = (short)eh;
        s_el[nn * 72 + jloc] = (short)f2bf(e - bf2f(eh));
        float se = e;
        se += __shfl_xor(se, 16, 64);
        se += __shfl_xor(se, 32, 64);
        if (lane < 16) s_sefp[(wv << 4) + lane] = se;
    }
    __syncthreads();

    // ---- phase T: wave = 16-k N-tile; A = e hi/lo, B = U direct frags ----
    {
        v4f tacc = {0.f, 0.f, 0.f, 0.f};
        const int k0 = wv << 4;
        #pragma unroll
        for (int jc = 0; jc < 2; ++jc) {
            v8s aeh = *(const v8s*)&s_eh[nn * 72 + (jc << 5) + (quad << 3)];
            v8s ael = *(const v8s*)&s_el[nn * 72 + (jc << 5) + (quad << 3)];
            short bu[8];
            #pragma unroll
            for (int jj = 0; jj < 8; ++jj) {
                int jrow = (jc << 5) + (quad << 3) + jj;
                int rk = (k0 + nn + ((jrow & 15) << 3)) & 255;
                bu[jj] = s_U[(jrow << 8) + rk];
            }
            v8s bf = (v8s){bu[0], bu[1], bu[2], bu[3], bu[4], bu[5], bu[6], bu[7]};
            tacc = __builtin_amdgcn_mfma_f32_16x16x32_bf16(aeh, bf, tacc, 0, 0, 0);
            tacc = __builtin_amdgcn_mfma_f32_16x16x32_bf16(ael, bf, tacc, 0, 0, 0);
        }
        #pragma unroll
        for (int r = 0; r < 4; ++r) {
            int i = (quad << 2) + r;
            tpart_out[(((((p << 6) + bg) << 4) + i) << 8) + k0 + nn] = tacc[r];
        }
    }
    if (tid < 16) {
        float ss = 0.f;
        #pragma unroll
        for (int w = 0; w < 16; ++w) ss += s_sefp[(w << 4) + tid];
        sefpart_out[(p << 10) + (bg << 4) + tid] = ss;
    }
}

// ---------------------------------------------------------------------------
extern "C" void kernel_launch(void* const* d_in, const int* in_sizes, int n_in,
                              void* d_out, int out_size, void* d_ws, size_t ws_size,
                              hipStream_t stream) {
    const float* U = (const float*)d_in[0];   // [32,1024,256]
    const float* W = (const float*)d_in[1];   // [256,2048]
    float* out = (float*)d_out;               // [32,32,64]
    float* ws = (float*)d_ws;

    // ws: 5,128,192 floats + 524,288 + 8,388,608 shorts  (~38.3 MB)
    float* t0p   = ws;                  // [32][16][256]      = 131,072
    float* WT    = t0p + 131072;        // [2048][256]        = 524,288
    float* wsum  = WT + 524288;         // [64][16][256]      = 262,144
    float* tp    = wsum + 262144;       // [16][64][16][256]  = 4,194,304
    float* sef   = tp + 4194304;        // [16][64][16]       = 16,384
    short* wbt_h = (short*)(sef + 16384);    // [64][16][256] shorts (rotated)
    short* wbt_l = wbt_h + 262144;
    short* Ubf16 = wbt_l + 262144;           // [32][1024][256] shorts (rotated)

    k_init<<<1152, 256, 0, stream>>>(U, W, t0p, WT, Ubf16);
    k_sv<<<1024, 256, 0, stream>>>(t0p, nullptr, nullptr, W, WT, wsum,
                                   wbt_h, wbt_l, out, 0, 0);
    k_pass<<<1024, 1024, 0, stream>>>(Ubf16, wbt_h, wbt_l, tp, sef);
    k_sv<<<1024, 256, 0, stream>>>(t0p, tp, sef, W, WT, wsum,
                                   wbt_h, wbt_l, out, 1, 0);
    k_pass<<<1024, 1024, 0, stream>>>(Ubf16, wbt_h, wbt_l, tp, sef);
    k_sv<<<1024, 256, 0, stream>>>(t0p, tp, sef, W, WT, wsum,
                                   wbt_h, wbt_l, out, 1, 1);
}